// Round 2
// baseline (325.205 us; speedup 1.0000x reference)
//
#include <hip/hip_runtime.h>
#include <cstdint>

// Problem constants (fixed by the reference setup)
#define BB   16      // batch
#define AA   16      // annotations per image
#define KK   80      // classes
#define NLEV 5       // pyramid levels (strides 8..128)
#define PP   21824   // total pyramid positions

// ---- mask kernel geometry (phase 0/1 of the old fused kernel) ----
#define POS_PER_BLK 128
#define NBLK_A ((PP + POS_PER_BLK - 1) / POS_PER_BLK)   // 171

// ---- focal streaming kernel geometry ----
#define VV   (PP * KK / 4)            // 436480 float4 per image
#define UB   8                        // float4s per thread
#define CHUNK (256 * UB)              // 2048 float4 per block
#define NBLK_B ((VV + CHUNK - 1) / CHUNK)   // 214

// ---------------- workspace layout (bytes, 16-aligned) ----------------
// 0       : uint scm  [BB][KK]        per-image class->annotation bitmask (5120 B)
// 5120    : uint smask[BB][PP]        em | (im<<16) per position          (1396736 B)
// 1401856 : float pr  [BB][NBLK_A]    reg-loss partials
// 1412800 : int   pn  [BB][NBLK_A]    n_eff partials
// 1423744 : float pc  [BB][NBLK_B]    cls-loss partials
// All slots written unconditionally -> no zero-init, NO atomics.

// Projected-box bounds, identical arithmetic to the reference.
__device__ __forceinline__ void compute_bounds(float x1, float y1, float x2, float y2,
                                               float s, int* o, float* q)
{
#pragma clang fp contract(off)
    float p0 = floorf((x1 + s - 1.0f) / s);
    float p1 = floorf((y1 + s - 1.0f) / s);
    float p2 = floorf((x2 + s - 1.0f) / s);
    float p3 = floorf((y2 + s - 1.0f) / s);
    float pw = p2 - p0, ph = p3 - p1;
    float e0 = p0 + 0.4f * pw,  e1 = p1 + 0.4f * ph;
    float e2 = p2 - 0.4f * pw,  e3 = p3 - 0.4f * ph;
    float i0 = p0 + 0.25f * pw, i1 = p1 + 0.25f * ph;
    float i2 = p2 - 0.25f * pw, i3 = p3 - 0.25f * ph;
    o[0] = (int)floorf(e0);          // eff x >=
    o[1] = (int)floorf(e2 + 1.0f);   // eff x <=
    o[2] = (int)floorf(e1);          // eff y >=
    o[3] = (int)floorf(e3 + 1.0f);   // eff y <=
    o[4] = (int)floorf(i0 + 1.0f);   // ign x >=
    o[5] = (int)floorf(i2);          // ign x <=
    o[6] = (int)floorf(i1 + 1.0f);   // ign y >=
    o[7] = (int)floorf(i3);          // ign y <=
    q[0] = p0; q[1] = p1; q[2] = p2; q[3] = p3;
}

__device__ __forceinline__ float focal_term(float c, unsigned int em,
                                            unsigned int im, unsigned int cm)
{
    float cc  = fminf(fmaxf(c, 1e-4f), 1.0f - 1e-4f);
    bool  pos = (em & cm) != 0;
    bool  ign = (!pos) && ((im & cm) != 0);
    float arg = pos ? cc : (1.0f - cc);   // log argument
    float fwt = 1.0f - arg;               // == (pos ? 1-cc : cc)
    float af  = pos ? 0.25f : 0.75f;
    float l   = af * fwt * fwt * (-__logf(arg));
    return ign ? 0.0f : l;
}

// -------------------------------------------------------------------
// Kernel A: masks + reg loss (phases 0/1 of the old fused kernel).
// Writes per-position em|im<<16 and per-image class bitmask table to
// workspace; reduces reg-loss / n_eff partials.  ~4 us.
// -------------------------------------------------------------------
__global__ void __launch_bounds__(256)
mask_kernel(const float4* __restrict__ reg4,     // B*PP
            const float* __restrict__ ann,       // B*A*5
            const int* __restrict__ xg, const int* __restrict__ yg,
            const int* __restrict__ lev,
            unsigned int* __restrict__ smask_g,  // B*PP
            unsigned int* __restrict__ scm_g,    // B*KK
            float* __restrict__ pr, int* __restrict__ pn)
{
    __shared__ int   sb[AA * NLEV * 8];
    __shared__ float sp[AA * NLEV * 4];
    __shared__ int   scid[AA];
    __shared__ float swr[4];
    __shared__ int   swn[4];

    const int  b    = blockIdx.y;
    const int  t    = threadIdx.x;
    const int  p0   = blockIdx.x * POS_PER_BLK;
    const bool full = (blockIdx.x < NBLK_A - 1);
    const int  npos = full ? POS_PER_BLK : (PP - (NBLK_A - 1) * POS_PER_BLK); // 128 or 64

    const float* annb = ann + b * AA * 5;

    // ---- role-specific ann loads into registers ----
    float bx0 = 0, bx1 = 0, bx2 = 0, bx3 = 0, cid1 = 0;
    float cidv[AA];
    const bool do_scm = (blockIdx.x == 0) && (t >= 128) && (t < 128 + KK);
    if (t < AA * NLEV) {                       // 80 bounds threads
        int a = t / NLEV;
        bx0 = annb[a * 5 + 0]; bx1 = annb[a * 5 + 1];
        bx2 = annb[a * 5 + 2]; bx3 = annb[a * 5 + 3];
    } else if (do_scm) {                       // 80 clsmask threads, block x==0 only
#pragma unroll
        for (int a = 0; a < AA; ++a) cidv[a] = annb[a * 5 + 4];
    } else if (t >= 224 && t < 224 + AA) {     // 16 scid threads
        cid1 = annb[(t - 224) * 5 + 4];
    }

    // ---- grid + regression for phase 1 ----
    const int pidx = p0 + ((t < npos) ? t : 0);
    int    x  = xg[pidx], y = yg[pidx], li = lev[pidx];
    float4 r4 = reg4[(size_t)b * PP + pidx];

    // ---- phase 0: registers -> LDS / global ----
    if (t < AA * NLEV) {
        int l = t % NLEV;
        compute_bounds(bx0, bx1, bx2, bx3, (float)(8 << l), &sb[t * 8], &sp[t * 4]);
    } else if (do_scm) {
        int k = t - 128;
        unsigned int m = 0;
#pragma unroll
        for (int a = 0; a < AA; ++a)
            if ((int)cidv[a] == k) m |= (1u << a);
        scm_g[b * KK + k] = m;
    } else if (t >= 224 && t < 224 + AA) {
        scid[t - 224] = (int)cid1;
    }
    __syncthreads();

    // ---- phase 1: position masks -> global, IoU reg loss ----
    float my_r = 0.0f; int my_n = 0;
    if (t < npos) {
        unsigned int em = 0, im = 0;
        for (int a = 0; a < AA; ++a) {
            const int* o = &sb[(a * NLEV + li) * 8];
            int me = (x >= o[0]) & (x <= o[1]) & (y >= o[2]) & (y <= o[3]);
            int mi = (x >= o[4]) & (x <= o[5]) & (y >= o[6]) & (y <= o[7]);
            em |= (unsigned int)me << a;
            im |= (unsigned int)mi << a;
        }
        smask_g[(size_t)b * PP + pidx] = em | (im << 16);

        // distinct positive classes at this position
        unsigned long long lo = 0; unsigned int hi = 0;
        unsigned int m = em;
        while (m) {
            int a = __ffs(m) - 1; m &= m - 1;
            int c = scid[a];
            if (c < 64) lo |= 1ull << c; else hi |= 1u << (c - 64);
        }
        int np = __popcll(lo) + __popc(hi);

        // box of LAST covering annotation (default A-1 when none)
        int last = em ? (31 - __clz(em)) : (AA - 1);
        const float* pb = &sp[(last * NLEV + li) * 4];
        float xf = (float)x, yf = (float)y;
        float t0 = (xf - pb[0]) * 0.25f;
        float t1 = (pb[2] - xf) * 0.25f;
        float t2 = (yf - pb[1]) * 0.25f;
        float t3 = (pb[3] - yf) * 0.25f;
        float x_gt = (t2 + t3 + 1.0f) * (t0 + t1 + 1.0f);
        float x_pr = (r4.z + r4.w + 1.0f) * (r4.x + r4.y + 1.0f);
        float ih = fminf(t2, r4.z) + fminf(t3, r4.w) + 1.0f;
        float iw = fminf(t0, r4.x) + fminf(t1, r4.y) + 1.0f;
        float inter = ih * iw;
        float iou = inter / (x_pr + x_gt - inter);
        iou = fminf(fmaxf(iou, 1e-4f), 1.0f - 1e-4f);
        my_r = -logf(iou) * (float)np;
        my_n = np;
    }

    for (int off = 32; off > 0; off >>= 1) {
        my_r += __shfl_down(my_r, off);
        my_n += __shfl_down(my_n, off);
    }
    int lane = t & 63, wv = t >> 6;
    if (lane == 0) { swr[wv] = my_r; swn[wv] = my_n; }
    __syncthreads();
    if (t == 0) {
        int slot = b * NBLK_A + blockIdx.x;
        pr[slot] = swr[0] + swr[1] + swr[2] + swr[3];
        pn[slot] = swn[0] + swn[1] + swn[2] + swn[3];
    }
}

// -------------------------------------------------------------------
// Kernel B: barrier-free cls stream (the 111.7 MB).
// Stage 448 B of position masks + 320 B of class masks to LDS, ONE
// barrier, THEN issue the 8 cls float4 loads.  No barrier ever sits
// behind an in-flight cls load -> no vmcnt(0) drain stall.
// Low VGPR, no role divergence -> high occupancy streaming.
// -------------------------------------------------------------------
__global__ void __launch_bounds__(256)
focal_kernel(const float4* __restrict__ cls4,          // B*VV
             const unsigned int* __restrict__ smask_g, // B*PP
             const uint4* __restrict__ scm_g,          // B*(KK/4)
             float* __restrict__ pc)
{
    __shared__ uint4        s_scm[KK / 4];   // 320 B
    __shared__ unsigned int s_mk[112];       // max 104 positions per block
    __shared__ float        swc[4];

    const int b  = blockIdx.y;
    const int bx = blockIdx.x;
    const int t  = threadIdx.x;
    const int base  = bx * CHUNK;
    const int pl_lo = base / 20;                      // first position this block touches

    // stage (two disjoint thread ranges so loads issue in parallel)
    if (t < KK / 4) s_scm[t] = scm_g[b * (KK / 4) + t];
    const int cnt = min(112, PP - pl_lo);             // positions covered: <= 104
    if (t >= 32 && (t - 32) < cnt)
        s_mk[t - 32] = smask_g[(size_t)b * PP + pl_lo + (t - 32)];
    __syncthreads();    // drains only the tiny staging loads

    // ---- issue ALL cls loads after the barrier ----
    float4 c4[UB];
    const float4* cb = cls4 + (size_t)b * VV + base;
#pragma unroll
    for (int u = 0; u < UB; ++u) {
        int off = t + 256 * u;
        if (base + off < VV) c4[u] = cb[off];
    }

    // ---- consume in FIFO order, pure register/LDS compute ----
    float acc = 0.0f;
#pragma unroll
    for (int u = 0; u < UB; ++u) {
        int off = base + t + 256 * u;
        if (off < VV) {
            unsigned int uoff = (unsigned int)off;
            unsigned int pl = uoff / 20u;
            unsigned int k4 = uoff - pl * 20u;
            unsigned int mk = s_mk[pl - (unsigned int)pl_lo];
            unsigned int em = mk & 0xFFFFu, im = mk >> 16;
            uint4 cm = s_scm[k4];
            acc += focal_term(c4[u].x, em, im, cm.x)
                 + focal_term(c4[u].y, em, im, cm.y)
                 + focal_term(c4[u].z, em, im, cm.z)
                 + focal_term(c4[u].w, em, im, cm.w);
        }
    }

    // ---- block reduce -> plain store to distinct slot ----
    for (int off = 32; off > 0; off >>= 1) acc += __shfl_down(acc, off);
    if ((t & 63) == 0) swc[t >> 6] = acc;
    __syncthreads();    // all loads already consumed; no drain cost
    if (t == 0)
        pc[b * NBLK_B + bx] = swc[0] + swc[1] + swc[2] + swc[3];
}

// -------------------------------------------------------------------
// Final reduce: 16 images x (214 cls + 171 reg) partials -> 2 outputs.
// -------------------------------------------------------------------
__global__ void final_kernel(const float* __restrict__ pc,
                             const float* __restrict__ pr,
                             const int* __restrict__ pn,
                             float* __restrict__ out)
{
    __shared__ float sc[BB], sr[BB];
    int t = threadIdx.x;          // 256
    int b = t >> 4, chunk = t & 15;
    float cs = 0.0f, rs = 0.0f; int ns = 0;
    for (int i = chunk; i < NBLK_B; i += 16) cs += pc[b * NBLK_B + i];
    for (int i = chunk; i < NBLK_A; i += 16) {
        rs += pr[b * NBLK_A + i];
        ns += pn[b * NBLK_A + i];
    }
    for (int off = 8; off > 0; off >>= 1) {
        cs += __shfl_down(cs, off, 16);
        rs += __shfl_down(rs, off, 16);
        ns += __shfl_down(ns, off, 16);
    }
    if (chunk == 0) {
        float d = fmaxf((float)ns, 1.0f);
        sc[b] = cs / d;
        sr[b] = (ns > 0) ? (rs / d) : 0.0f;
    }
    __syncthreads();
    if (t == 0) {
        float C = 0.0f, R = 0.0f;
        for (int i = 0; i < BB; ++i) { C += sc[i]; R += sr[i]; }
        out[0] = C * (1.0f / BB);
        out[1] = R * (1.0f / BB);
    }
}

extern "C" void kernel_launch(void* const* d_in, const int* in_sizes, int n_in,
                              void* d_out, int out_size, void* d_ws, size_t ws_size,
                              hipStream_t stream)
{
    const float* cls = (const float*)d_in[0];
    const float* reg = (const float*)d_in[1];
    const float* ann = (const float*)d_in[2];
    // d_in[3] = image (unused)
    const int* xg = (const int*)d_in[4];
    const int* yg = (const int*)d_in[5];
    const int* lv = (const int*)d_in[6];
    float* out = (float*)d_out;

    char* ws = (char*)d_ws;
    unsigned int* scm   = (unsigned int*)(ws + 0);        // 5120 B
    unsigned int* smask = (unsigned int*)(ws + 5120);     // 1396736 B
    float* pr = (float*)(ws + 1401856);
    int*   pn = (int*)(ws + 1412800);
    float* pc = (float*)(ws + 1423744);

    // No memset needed: every workspace slot consumed is written
    // unconditionally by mask_kernel / focal_kernel.
    dim3 gridA(NBLK_A, BB);
    mask_kernel<<<gridA, 256, 0, stream>>>((const float4*)reg, ann, xg, yg, lv,
                                           smask, scm, pr, pn);

    dim3 gridB(NBLK_B, BB);
    focal_kernel<<<gridB, 256, 0, stream>>>((const float4*)cls, smask,
                                            (const uint4*)scm, pc);

    final_kernel<<<1, 256, 0, stream>>>(pc, pr, pn, out);
}

// Round 3
// 308.286 us; speedup vs baseline: 1.0549x; 1.0549x over previous
//
#include <hip/hip_runtime.h>
#include <cstdint>

// Problem constants (fixed by the reference setup)
#define BB   16      // batch
#define AA   16      // annotations per image
#define KK   80      // classes
#define NLEV 5       // pyramid levels (strides 8..128)
#define PP   21824   // total pyramid positions

#define POS_PER_BLK 128
#define NBLK_X ((PP + POS_PER_BLK - 1) / POS_PER_BLK)   // 171; blocks 0..169 full, block 170 has 64 pos
// ---------------- workspace layout (bytes) ----------------
// 0     : float pc[BB][NBLK_X]   per-block cls partial  (10944 B)
// 12288 : float pr[BB][NBLK_X]
// 24576 : int   pn[BB][NBLK_X]
// All slots written unconditionally -> no zero-init, NO atomics.

// non-temporal float4 (read-once streams: cls, reg)
typedef float f4 __attribute__((ext_vector_type(4)));

// Projected-box bounds, identical arithmetic to the reference.
__device__ __forceinline__ void compute_bounds(float x1, float y1, float x2, float y2,
                                               float s, int* o, float* q)
{
#pragma clang fp contract(off)
    float p0 = floorf((x1 + s - 1.0f) / s);
    float p1 = floorf((y1 + s - 1.0f) / s);
    float p2 = floorf((x2 + s - 1.0f) / s);
    float p3 = floorf((y2 + s - 1.0f) / s);
    float pw = p2 - p0, ph = p3 - p1;
    float e0 = p0 + 0.4f * pw,  e1 = p1 + 0.4f * ph;
    float e2 = p2 - 0.4f * pw,  e3 = p3 - 0.4f * ph;
    float i0 = p0 + 0.25f * pw, i1 = p1 + 0.25f * ph;
    float i2 = p2 - 0.25f * pw, i3 = p3 - 0.25f * ph;
    o[0] = (int)floorf(e0);          // eff x >=
    o[1] = (int)floorf(e2 + 1.0f);   // eff x <=
    o[2] = (int)floorf(e1);          // eff y >=
    o[3] = (int)floorf(e3 + 1.0f);   // eff y <=
    o[4] = (int)floorf(i0 + 1.0f);   // ign x >=
    o[5] = (int)floorf(i2);          // ign x <=
    o[6] = (int)floorf(i1 + 1.0f);   // ign y >=
    o[7] = (int)floorf(i3);          // ign y <=
    q[0] = p0; q[1] = p1; q[2] = p2; q[3] = p3;
}

__device__ __forceinline__ float focal_term(float c, unsigned int em,
                                            unsigned int im, unsigned int cm)
{
    float cc  = fminf(fmaxf(c, 1e-4f), 1.0f - 1e-4f);
    bool  pos = (em & cm) != 0;
    bool  ign = (!pos) && ((im & cm) != 0);
    float arg = pos ? cc : (1.0f - cc);   // log argument
    float fwt = 1.0f - arg;               // == (pos ? 1-cc : cc)
    float af  = pos ? 0.25f : 0.75f;
    float l   = af * fwt * fwt * (-__logf(arg));
    return ign ? 0.0f : l;
}

// -------------------------------------------------------------------
// Fused kernel, 128 positions/block (2736 blocks for overlap).
// Round-0 proven structure; cls/reg loads are NON-TEMPORAL (read-once
// streams must not pollute L2/L3).  Load issue order = consumption
// order; only TWO barriers per block; phase 2 pure register compute.
// Epilogue: plain stores to distinct per-block slots (no atomics).
// -------------------------------------------------------------------
__global__ void __launch_bounds__(256)
fused_kernel(const f4* __restrict__ cls4,        // B * (P*K/4)
             const f4* __restrict__ reg4,        // B*P
             const float* __restrict__ ann,      // B*A*5
             const int* __restrict__ xg, const int* __restrict__ yg,
             const int* __restrict__ lev,
             float* __restrict__ pc, float* __restrict__ pr,
             int* __restrict__ pn)
{
    __shared__ int   sb[AA * NLEV * 8];
    __shared__ float sp[AA * NLEV * 4];
    __shared__ int   scid[AA];
    __shared__ uint4 scm[KK / 4];
    __shared__ unsigned int smask[POS_PER_BLK];
    __shared__ float swc[4], swr[4];
    __shared__ int   swn[4];

    const int  b    = blockIdx.y;
    const int  t    = threadIdx.x;
    const int  p0   = blockIdx.x * POS_PER_BLK;
    const bool full = (blockIdx.x < NBLK_X - 1);
    const int  npos = full ? POS_PER_BLK : (PP - (NBLK_X - 1) * POS_PER_BLK); // 128 or 64

    const float* annb = ann + b * AA * 5;

    // ---- issue 1: role-specific ann loads into REGISTERS ----
    float bx0 = 0, bx1 = 0, bx2 = 0, bx3 = 0, cid1 = 0;
    float cidv[AA];
    if (t < AA * NLEV) {                       // 80 bounds threads
        int a = t / NLEV;
        bx0 = annb[a * 5 + 0]; bx1 = annb[a * 5 + 1];
        bx2 = annb[a * 5 + 2]; bx3 = annb[a * 5 + 3];
    } else if (t >= 128 && t < 128 + KK) {     // 80 clsmask threads (16 shared addrs, L1 broadcast)
#pragma unroll
        for (int a = 0; a < AA; ++a) cidv[a] = annb[a * 5 + 4];
    } else if (t >= 224 && t < 224 + AA) {     // 16 scid threads
        cid1 = annb[(t - 224) * 5 + 4];
    }

    // ---- issue 2: grid + regression (consumed in phase 1) ----
    const int pidx = p0 + ((t < npos) ? t : 0);
    int x  = xg[pidx], y = yg[pidx], li = lev[pidx];
    f4  r4 = __builtin_nontemporal_load(reg4 + (size_t)b * PP + pidx);

    // ---- issue 3: ALL cls float4s for this thread (consumed phase 2) ----
    const int V = PP * KK / 4;
    const f4* cbase = cls4 + (size_t)b * V + (size_t)p0 * (KK / 4);
    f4 c0[10];
    if (full) {
#pragma unroll
        for (int u = 0; u < 10; ++u) c0[u] = __builtin_nontemporal_load(cbase + t + 256 * u);
    } else {
#pragma unroll
        for (int u = 0; u < 5; ++u)  c0[u] = __builtin_nontemporal_load(cbase + t + 256 * u);
    }

    // ---- phase 0: compute from registers -> LDS (cls still in flight) ----
    if (t < AA * NLEV) {
        int l = t % NLEV;
        compute_bounds(bx0, bx1, bx2, bx3, (float)(8 << l), &sb[t * 8], &sp[t * 4]);
    } else if (t >= 128 && t < 128 + KK) {
        int k = t - 128;
        unsigned int m = 0;
#pragma unroll
        for (int a = 0; a < AA; ++a)
            if ((int)cidv[a] == k) m |= (1u << a);
        ((unsigned int*)scm)[k] = m;
    } else if (t >= 224 && t < 224 + AA) {
        scid[t - 224] = (int)cid1;
    }
    __syncthreads();   // B1

    // ---- phase 1: position masks + IoU reg loss ----
    float my_r = 0.0f; int my_n = 0;
    if (t < npos) {
        unsigned int em = 0, im = 0;
        for (int a = 0; a < AA; ++a) {
            const int* o = &sb[(a * NLEV + li) * 8];
            int me = (x >= o[0]) & (x <= o[1]) & (y >= o[2]) & (y <= o[3]);
            int mi = (x >= o[4]) & (x <= o[5]) & (y >= o[6]) & (y <= o[7]);
            em |= (unsigned int)me << a;
            im |= (unsigned int)mi << a;
        }
        smask[t] = em | (im << 16);

        // distinct positive classes at this position
        unsigned long long lo = 0; unsigned int hi = 0;
        unsigned int m = em;
        while (m) {
            int a = __ffs(m) - 1; m &= m - 1;
            int c = scid[a];
            if (c < 64) lo |= 1ull << c; else hi |= 1u << (c - 64);
        }
        int np = __popcll(lo) + __popc(hi);

        // box of LAST covering annotation (default A-1 when none)
        int last = em ? (31 - __clz(em)) : (AA - 1);
        const float* pb = &sp[(last * NLEV + li) * 4];
        float xf = (float)x, yf = (float)y;
        float t0 = (xf - pb[0]) * 0.25f;
        float t1 = (pb[2] - xf) * 0.25f;
        float t2 = (yf - pb[1]) * 0.25f;
        float t3 = (pb[3] - yf) * 0.25f;
        float x_gt = (t2 + t3 + 1.0f) * (t0 + t1 + 1.0f);
        float x_pr = (r4.z + r4.w + 1.0f) * (r4.x + r4.y + 1.0f);
        float ih = fminf(t2, r4.z) + fminf(t3, r4.w) + 1.0f;
        float iw = fminf(t0, r4.x) + fminf(t1, r4.y) + 1.0f;
        float inter = ih * iw;
        float iou = inter / (x_pr + x_gt - inter);
        iou = fminf(fmaxf(iou, 1e-4f), 1.0f - 1e-4f);
        my_r = -logf(iou) * (float)np;
        my_n = np;
    }
    __syncthreads();   // B2

    // ---- phase 2: pure compute on prefetched registers ----
    float acc = 0.0f;
    if (full) {
#pragma unroll
        for (int u = 0; u < 10; ++u) {
            unsigned int il = (unsigned int)(t + 256 * u);
            unsigned int pl = il / 20u, k4 = il - pl * 20u;
            unsigned int mk = smask[pl];
            unsigned int em = mk & 0xFFFFu, im = mk >> 16;
            uint4 cm = scm[k4];
            acc += focal_term(c0[u].x, em, im, cm.x)
                 + focal_term(c0[u].y, em, im, cm.y)
                 + focal_term(c0[u].z, em, im, cm.z)
                 + focal_term(c0[u].w, em, im, cm.w);
        }
    } else {
#pragma unroll
        for (int u = 0; u < 5; ++u) {
            unsigned int il = (unsigned int)(t + 256 * u);
            unsigned int pl = il / 20u, k4 = il - pl * 20u;
            unsigned int mk = smask[pl];
            unsigned int em = mk & 0xFFFFu, im = mk >> 16;
            uint4 cm = scm[k4];
            acc += focal_term(c0[u].x, em, im, cm.x)
                 + focal_term(c0[u].y, em, im, cm.y)
                 + focal_term(c0[u].z, em, im, cm.z)
                 + focal_term(c0[u].w, em, im, cm.w);
        }
    }

    // ---- epilogue: block reduce -> PLAIN store to distinct slot ----
    for (int off = 32; off > 0; off >>= 1) {
        acc  += __shfl_down(acc,  off);
        my_r += __shfl_down(my_r, off);
        my_n += __shfl_down(my_n, off);
    }
    int lane = t & 63, wv = t >> 6;
    if (lane == 0) { swc[wv] = acc; swr[wv] = my_r; swn[wv] = my_n; }
    __syncthreads();
    if (t == 0) {
        int slot = b * NBLK_X + blockIdx.x;
        pc[slot] = swc[0] + swc[1] + swc[2] + swc[3];
        pr[slot] = swr[0] + swr[1] + swr[2] + swr[3];
        pn[slot] = swn[0] + swn[1] + swn[2] + swn[3];
    }
}

// -------------------------------------------------------------------
// Final reduce: 16 images x 171 partials -> 2 outputs. One block.
// -------------------------------------------------------------------
__global__ void final_kernel(const float* __restrict__ pc,
                             const float* __restrict__ pr,
                             const int* __restrict__ pn,
                             float* __restrict__ out)
{
    __shared__ float sc[BB], sr[BB];
    int t = threadIdx.x;          // 256
    int b = t >> 4, chunk = t & 15;
    float cs = 0.0f, rs = 0.0f; int ns = 0;
    for (int i = chunk; i < NBLK_X; i += 16) {
        cs += pc[b * NBLK_X + i];
        rs += pr[b * NBLK_X + i];
        ns += pn[b * NBLK_X + i];
    }
    for (int off = 8; off > 0; off >>= 1) {
        cs += __shfl_down(cs, off, 16);
        rs += __shfl_down(rs, off, 16);
        ns += __shfl_down(ns, off, 16);
    }
    if (chunk == 0) {
        float d = fmaxf((float)ns, 1.0f);
        sc[b] = cs / d;
        sr[b] = (ns > 0) ? (rs / d) : 0.0f;
    }
    __syncthreads();
    if (t == 0) {
        float C = 0.0f, R = 0.0f;
        for (int i = 0; i < BB; ++i) { C += sc[i]; R += sr[i]; }
        out[0] = C * (1.0f / BB);
        out[1] = R * (1.0f / BB);
    }
}

extern "C" void kernel_launch(void* const* d_in, const int* in_sizes, int n_in,
                              void* d_out, int out_size, void* d_ws, size_t ws_size,
                              hipStream_t stream)
{
    const float* cls = (const float*)d_in[0];
    const float* reg = (const float*)d_in[1];
    const float* ann = (const float*)d_in[2];
    // d_in[3] = image (unused)
    const int* xg = (const int*)d_in[4];
    const int* yg = (const int*)d_in[5];
    const int* lv = (const int*)d_in[6];
    float* out = (float*)d_out;

    char* ws = (char*)d_ws;
    float* pc = (float*)(ws + 0);
    float* pr = (float*)(ws + 12288);
    int*   pn = (int*)(ws + 24576);

    // No memset needed: every partial slot is written unconditionally.
    dim3 grid(NBLK_X, BB);
    fused_kernel<<<grid, 256, 0, stream>>>((const f4*)cls, (const f4*)reg,
                                           ann, xg, yg, lv, pc, pr, pn);

    final_kernel<<<1, 256, 0, stream>>>(pc, pr, pn, out);
}